// Round 1
// baseline (320.929 us; speedup 1.0000x reference)
//
#include <hip/hip_runtime.h>

// ---------------- problem constants ----------------
#define N_ROWS 32768       // 32*32*32 spatial positions
#define N_EMB  1024
#define EMB_D  256
#define HW     1024        // 32*32

// d_out layout (floats)
#define OUT_ZQ      0
#define OUT_LOSS    8388608
#define OUT_PERP    8388609
#define OUT_NEAREST 8388610
#define OUT_IDX     41943042

// ws layout (bytes)
#define WS_KEYS   0          // 32768 * 8
#define WS_IDX    262144     // 32768 * 4
#define WS_HIST   393216     // 1024 * 4
#define WS_EMBT   524288     // 1 MB
#define WS_ZSQ    1572864    // 32768 * 4
#define WS_ESQ    1703936    // 1024 * 4
#define WS_LOSSP  1708032    // 32768 * 8
#define WS_TOTAL  1970176

typedef unsigned long long ull;

// ---------------- emb transpose: embT[d][c] = emb[c][d] ----------------
__global__ void embT_kernel(const float* __restrict__ emb, float* __restrict__ embT) {
    int c = blockIdx.x;        // 0..1023
    int d = threadIdx.x;       // 0..255
    embT[d * N_EMB + c] = emb[c * EMB_D + d];
}

// ---------------- row sums of squares, replicating numpy pairwise (128+128, 8-acc) ----
__device__ __forceinline__ float pairwise8_combine(const float r[8]) {
    return __fadd_rn(__fadd_rn(__fadd_rn(r[0], r[1]), __fadd_rn(r[2], r[3])),
                     __fadd_rn(__fadd_rn(r[4], r[5]), __fadd_rn(r[6], r[7])));
}

__global__ void zsq_kernel(const float* __restrict__ z, float* __restrict__ zsq) {
    int n = blockIdx.x * 256 + threadIdx.x;        // row id
    const float* p = z + ((size_t)(n >> 10) << 18) + (n & (HW - 1));
    float tot[2];
    #pragma unroll
    for (int h = 0; h < 2; ++h) {
        float r[8];
        #pragma unroll
        for (int i = 0; i < 8; ++i) {
            float x = p[(size_t)(h * 128 + i) << 10];
            r[i] = __fmul_rn(x, x);
        }
        for (int k = 8; k < 128; k += 8) {
            #pragma unroll
            for (int i = 0; i < 8; ++i) {
                float x = p[(size_t)(h * 128 + k + i) << 10];
                r[i] = __fadd_rn(r[i], __fmul_rn(x, x));
            }
        }
        tot[h] = pairwise8_combine(r);
    }
    zsq[n] = __fadd_rn(tot[0], tot[1]);
}

__global__ void esq_kernel(const float* __restrict__ emb, float* __restrict__ esq) {
    int c = blockIdx.x * 256 + threadIdx.x;        // 0..1023
    const float* p = emb + (size_t)c * EMB_D;
    float tot[2];
    #pragma unroll
    for (int h = 0; h < 2; ++h) {
        float r[8];
        #pragma unroll
        for (int i = 0; i < 8; ++i) {
            float x = p[h * 128 + i];
            r[i] = __fmul_rn(x, x);
        }
        for (int k = 8; k < 128; k += 8) {
            #pragma unroll
            for (int i = 0; i < 8; ++i) {
                float x = p[h * 128 + k + i];
                r[i] = __fadd_rn(r[i], __fmul_rn(x, x));
            }
        }
        tot[h] = pairwise8_combine(r);
    }
    esq[c] = __fadd_rn(tot[0], tot[1]);
}

// ---------------- fused distance GEMM + argmin ----------------
// grid 2048 = 256 row-blocks (BM=128) x 8 col-blocks (BN=128); block 256 threads
// 16x16 thread grid, 8x8 micro-tile, KC=16
__global__ __launch_bounds__(256) void gemm_argmin(
        const float* __restrict__ z, const float* __restrict__ embT,
        const float* __restrict__ zsq, const float* __restrict__ esq,
        ull* __restrict__ keys) {
    __shared__ float zT[16][128];
    __shared__ float eT[16][128];
    __shared__ ull lbest[128];

    int bid = blockIdx.x;
    int rb = bid >> 3, cb = bid & 7;
    int row0 = rb << 7, col0 = cb << 7;
    int t = threadIdx.x;
    int tx = t & 15, ty = t >> 4;

    if (t < 128) lbest[t] = ~0ULL;

    // rows row0..row0+127 live in batch b = row0>>10, contiguous hw range
    const float* zb = z + ((size_t)(row0 >> 10) << 18) + (row0 & (HW - 1));
    const float* eb = embT + col0;

    float acc[8][8];
    #pragma unroll
    for (int i = 0; i < 8; ++i)
        #pragma unroll
        for (int j = 0; j < 8; ++j) acc[i][j] = 0.0f;

    for (int k0 = 0; k0 < EMB_D; k0 += 16) {
        float4 a0 = *(const float4*)(zb + (size_t)(k0 + ty) * HW + tx * 8);
        float4 a1 = *(const float4*)(zb + (size_t)(k0 + ty) * HW + tx * 8 + 4);
        float4 b0 = *(const float4*)(eb + (size_t)(k0 + ty) * N_EMB + tx * 8);
        float4 b1 = *(const float4*)(eb + (size_t)(k0 + ty) * N_EMB + tx * 8 + 4);
        __syncthreads();
        *(float4*)&zT[ty][tx * 8]     = a0;
        *(float4*)&zT[ty][tx * 8 + 4] = a1;
        *(float4*)&eT[ty][tx * 8]     = b0;
        *(float4*)&eT[ty][tx * 8 + 4] = b1;
        __syncthreads();
        #pragma unroll
        for (int kk = 0; kk < 16; ++kk) {
            float ar[8], br[8];
            *(float4*)&ar[0] = *(const float4*)&zT[kk][ty * 8];
            *(float4*)&ar[4] = *(const float4*)&zT[kk][ty * 8 + 4];
            *(float4*)&br[0] = *(const float4*)&eT[kk][tx * 8];
            *(float4*)&br[4] = *(const float4*)&eT[kk][tx * 8 + 4];
            #pragma unroll
            for (int i = 0; i < 8; ++i)
                #pragma unroll
                for (int j = 0; j < 8; ++j)
                    acc[i][j] = __builtin_fmaf(ar[i], br[j], acc[i][j]);
        }
    }

    // d = fl(fl(zsq + esq) - fl(2*dot)); packed key = (d_bits<<32)|col -> min picks
    // smallest d, ties to lowest index (matches np.argmin)
    #pragma unroll
    for (int i = 0; i < 8; ++i) {
        int r = ty * 8 + i;
        float zs = zsq[row0 + r];
        ull best = ~0ULL;
        #pragma unroll
        for (int j = 0; j < 8; ++j) {
            int c = col0 + tx * 8 + j;
            float t1 = __fadd_rn(zs, esq[c]);
            float d  = __fsub_rn(t1, __fmul_rn(2.0f, acc[i][j]));
            ull key = ((ull)__float_as_uint(d) << 32) | (unsigned)c;
            best = best < key ? best : key;
        }
        atomicMin(&lbest[r], best);
    }
    __syncthreads();
    if (t < 128) atomicMin(&keys[row0 + t], lbest[t]);
}

// ---------------- per-row finalize: idx, one-hot scatter, histogram ----------------
__global__ void finalize_rows(const ull* __restrict__ keys,
                              int* __restrict__ idxarr, float* __restrict__ out_idx,
                              float* __restrict__ nearest, int* __restrict__ hist) {
    int n = blockIdx.x * 256 + threadIdx.x;
    int idx = (int)(unsigned)(keys[n] & 0xFFFFFFFFu);
    idxarr[n] = idx;
    out_idx[n] = (float)idx;
    nearest[(size_t)n * N_EMB + idx] = 1.0f;
    atomicAdd(&hist[idx], 1);
}

// ---------------- zq gather + straight-through output + loss partials ----------------
__global__ void zq_loss_kernel(const float* __restrict__ z, const float* __restrict__ emb,
                               const int* __restrict__ idxarr, float* __restrict__ outzq,
                               double* __restrict__ lossp) {
    int o = blockIdx.x * 256 + threadIdx.x;        // NCHW flat index
    int hw = o & (HW - 1);
    int c  = (o >> 10) & 255;
    int b  = o >> 18;
    int n  = (b << 10) | hw;
    int idx = idxarr[n];
    float zc = z[o];
    float zq = emb[idx * EMB_D + c];
    float diff = __fsub_rn(zq, zc);
    outzq[o] = __fadd_rn(zc, diff);                // zc + (zq - zc), same ops as ref
    float sq = __fmul_rn(diff, diff);

    __shared__ double sd[256];
    sd[threadIdx.x] = (double)sq;
    __syncthreads();
    for (int s = 128; s > 0; s >>= 1) {
        if (threadIdx.x < s) sd[threadIdx.x] += sd[threadIdx.x + s];
        __syncthreads();
    }
    if (threadIdx.x == 0) lossp[blockIdx.x] = sd[0];
}

// ---------------- scalars: loss + perplexity (deterministic reductions) ----------------
__global__ void finalize_scalars(const double* __restrict__ lossp,
                                 const int* __restrict__ hist,
                                 float* __restrict__ out_loss,
                                 float* __restrict__ out_perp) {
    __shared__ double sd[1024];
    int t = threadIdx.x;

    double s = 0.0;
    for (int i = 0; i < 32; ++i) s += lossp[t + (i << 10)];
    sd[t] = s;
    __syncthreads();
    for (int st = 512; st > 0; st >>= 1) {
        if (t < st) sd[t] += sd[t + st];
        __syncthreads();
    }
    if (t == 0) {
        double loss = 1.25 * (sd[0] / 8388608.0);  // mse + 0.25*mse
        *out_loss = (float)loss;
    }
    __syncthreads();

    float p = (float)hist[t] * (1.0f / 32768.0f);  // exact
    float term = __fmul_rn(p, logf(__fadd_rn(p, 1e-10f)));
    sd[t] = (double)term;
    __syncthreads();
    for (int st = 512; st > 0; st >>= 1) {
        if (t < st) sd[t] += sd[t + st];
        __syncthreads();
    }
    if (t == 0) *out_perp = expf(-(float)sd[0]);
}

// ---------------- launch ----------------
extern "C" void kernel_launch(void* const* d_in, const int* in_sizes, int n_in,
                              void* d_out, int out_size, void* d_ws, size_t ws_size,
                              hipStream_t stream) {
    const float* z   = (const float*)d_in[0];
    const float* emb = (const float*)d_in[1];
    float* out = (float*)d_out;
    char*  ws  = (char*)d_ws;

    ull*    keys   = (ull*)(ws + WS_KEYS);
    int*    idxarr = (int*)(ws + WS_IDX);
    int*    hist   = (int*)(ws + WS_HIST);
    float*  embT   = (float*)(ws + WS_EMBT);
    float*  zsq    = (float*)(ws + WS_ZSQ);
    float*  esq    = (float*)(ws + WS_ESQ);
    double* lossp  = (double*)(ws + WS_LOSSP);

    // re-init every call (harness does not re-poison between replays)
    hipMemsetAsync(keys, 0xFF, (size_t)N_ROWS * 8, stream);            // keys = UINT64_MAX
    hipMemsetAsync(hist, 0, (size_t)N_EMB * 4, stream);
    hipMemsetAsync(out + OUT_NEAREST, 0, (size_t)N_ROWS * N_EMB * 4, stream);

    embT_kernel<<<N_EMB, 256, 0, stream>>>(emb, embT);
    esq_kernel<<<N_EMB / 256, 256, 0, stream>>>(emb, esq);
    zsq_kernel<<<N_ROWS / 256, 256, 0, stream>>>(z, zsq);

    gemm_argmin<<<(N_ROWS / 128) * (N_EMB / 128), 256, 0, stream>>>(z, embT, zsq, esq, keys);

    finalize_rows<<<N_ROWS / 256, 256, 0, stream>>>(keys, idxarr,
                                                    out + OUT_IDX, out + OUT_NEAREST, hist);
    zq_loss_kernel<<<8388608 / 256, 256, 0, stream>>>(z, emb, idxarr, out, lossp);
    finalize_scalars<<<1, 1024, 0, stream>>>(lossp, hist,
                                             out + OUT_LOSS, out + OUT_PERP);
}

// Round 3
// 254.068 us; speedup vs baseline: 1.2632x; 1.2632x over previous
//
#include <hip/hip_runtime.h>

// ---------------- problem constants ----------------
#define N_ROWS 32768       // 32*32*32 spatial positions
#define N_EMB  1024
#define EMB_D  256
#define HW     1024        // 32*32

// d_out layout (floats)
#define OUT_ZQ      0
#define OUT_LOSS    8388608
#define OUT_PERP    8388609
#define OUT_NEAREST 8388610
#define OUT_IDX     41943042

// scratch inside the one-hot output region (consumed before onehot_rows overwrites)
// OUT_NEAREST byte offset = 33554440; round up to 16B
#define ZH_BYTE_OFF   33554448ULL
#define ZM_BYTE_OFF   (ZH_BYTE_OFF + 16777216ULL)   // 50331664
#define K2_BYTE_OFF   (ZM_BYTE_OFF + 16777216ULL)   // 67108880, keys2: 32768*32*8 = 8 MB

// ws layout (bytes)
#define WS_IDX    0          // 32768 * 4
#define WS_HIST   131072     // 1024 * 4
#define WS_ZSQ    135168     // 32768 * 4
#define WS_ESQ    266240     // 1024 * 4
#define WS_LOSSP  270336     // 32768 * 8
#define WS_EH     532480     // 1024*256*2
#define WS_EM     1056768    // 1024*256*2
#define WS_TOTAL  1581056

typedef unsigned long long ull;
typedef _Float16 half8 __attribute__((ext_vector_type(8)));
typedef float f32x4 __attribute__((ext_vector_type(4)));

__device__ __forceinline__ void gload16(const void* g, void* l) {
    __builtin_amdgcn_global_load_lds(
        (const __attribute__((address_space(1))) unsigned int*)g,
        (__attribute__((address_space(3))) unsigned int*)l, 16, 0, 0);
}

// ---------------- fp16 split of z, with [b][c][hw] -> [n][k] transpose ----------------
__global__ void split_z(const float* __restrict__ z,
                        _Float16* __restrict__ zh, _Float16* __restrict__ zm) {
    int b = blockIdx.x >> 4;
    int hw = ((blockIdx.x & 15) << 6) | (threadIdx.x & 63);
    int cpart = threadIdx.x >> 6;
    int n = (b << 10) | hw;
    const float* zp = z + ((size_t)b << 18) + hw;
    int cbeg = cpart << 6;
    for (int c0 = cbeg; c0 < cbeg + 64; c0 += 8) {
        half8 hv, mv;
        #pragma unroll
        for (int e = 0; e < 8; ++e) {
            float x = zp[(size_t)(c0 + e) << 10];
            _Float16 h = (_Float16)x;
            _Float16 m = (_Float16)(x - (float)h);
            hv[e] = h; mv[e] = m;
        }
        *(half8*)(zh + ((size_t)n << 8) + c0) = hv;
        *(half8*)(zm + ((size_t)n << 8) + c0) = mv;
    }
}

// ---------------- fp16 split of emb ----------------
__global__ void split_e(const float* __restrict__ emb,
                        _Float16* __restrict__ eh, _Float16* __restrict__ em) {
    int c = blockIdx.x;
    int k = threadIdx.x;
    float x = emb[c * EMB_D + k];
    _Float16 h = (_Float16)x;
    _Float16 m = (_Float16)(x - (float)h);
    eh[c * EMB_D + k] = h;
    em[c * EMB_D + k] = m;
}

// ---------------- row sums of squares, replicating numpy pairwise (128+128, 8-acc) ----
__device__ __forceinline__ float pairwise8_combine(const float r[8]) {
    return __fadd_rn(__fadd_rn(__fadd_rn(r[0], r[1]), __fadd_rn(r[2], r[3])),
                     __fadd_rn(__fadd_rn(r[4], r[5]), __fadd_rn(r[6], r[7])));
}

__global__ void zsq_kernel(const float* __restrict__ z, float* __restrict__ zsq) {
    int n = blockIdx.x * 256 + threadIdx.x;
    const float* p = z + ((size_t)(n >> 10) << 18) + (n & (HW - 1));
    float tot[2];
    #pragma unroll
    for (int h = 0; h < 2; ++h) {
        float r[8];
        #pragma unroll
        for (int i = 0; i < 8; ++i) {
            float x = p[(size_t)(h * 128 + i) << 10];
            r[i] = __fmul_rn(x, x);
        }
        for (int k = 8; k < 128; k += 8) {
            #pragma unroll
            for (int i = 0; i < 8; ++i) {
                float x = p[(size_t)(h * 128 + k + i) << 10];
                r[i] = __fadd_rn(r[i], __fmul_rn(x, x));
            }
        }
        tot[h] = pairwise8_combine(r);
    }
    zsq[n] = __fadd_rn(tot[0], tot[1]);
}

__global__ void esq_kernel(const float* __restrict__ emb, float* __restrict__ esq) {
    int c = blockIdx.x * 256 + threadIdx.x;
    const float* p = emb + (size_t)c * EMB_D;
    float tot[2];
    #pragma unroll
    for (int h = 0; h < 2; ++h) {
        float r[8];
        #pragma unroll
        for (int i = 0; i < 8; ++i) {
            float x = p[h * 128 + i];
            r[i] = __fmul_rn(x, x);
        }
        for (int k = 8; k < 128; k += 8) {
            #pragma unroll
            for (int i = 0; i < 8; ++i) {
                float x = p[h * 128 + k + i];
                r[i] = __fadd_rn(r[i], __fmul_rn(x, x));
            }
        }
        tot[h] = pairwise8_combine(r);
    }
    esq[c] = __fadd_rn(tot[0], tot[1]);
}

// ---------------- MFMA distance GEMM + per-(row,64col) top-2 keys ----------------
// grid 2048 = 256 row-blocks x 8 col-blocks; 256 threads = 4 waves (2x2), wave tile 64x64
__global__ __launch_bounds__(256) void gemm_mfma_argmin(
        const _Float16* __restrict__ zh, const _Float16* __restrict__ zm,
        const _Float16* __restrict__ eh, const _Float16* __restrict__ em,
        const float* __restrict__ zsq, const float* __restrict__ esq,
        ull* __restrict__ keys2) {
    __shared__ __align__(16) char lds[32768];   // A at 0 (16KB), B at 16384 (16KB)

    int t = threadIdx.x;
    int bid = blockIdx.x;
    int rb = bid >> 3, cb = bid & 7;
    int row0 = rb << 7, col0 = cb << 7;
    int lane = t & 63, wave = t >> 6;
    int wm = wave >> 1, wn = wave & 1;
    int l15 = lane & 15, lq = lane >> 4;

    // k0-invariant LDS read offsets (h; m = ^16)
    int aoff[4], boff[4];
    #pragma unroll
    for (int f = 0; f < 4; ++f) {
        int r = wm * 64 + f * 16 + l15;
        aoff[f] = r * 128 + ((lq * 32) ^ ((r & 7) << 4));
        int c = wn * 64 + f * 16 + l15;
        boff[f] = 16384 + c * 128 + ((lq * 32) ^ ((c & 7) << 4));
    }

    // staging: 8 issues x 256 threads x 16B = 32KB; decode inverse swizzle
    const _Float16* srcbase[8];
    int ldsoff[8];
    #pragma unroll
    for (int i = 0; i < 8; ++i) {
        int o = i * 4096 + t * 16;
        int isB = o >> 14;
        int ol = o & 16383;
        int row = ol >> 7;
        int raw = (ol & 127) ^ ((row & 7) << 4);
        int c8 = raw >> 5, s = (raw >> 4) & 1;
        const _Float16* base;
        if (!isB) base = (s ? zm : zh) + ((size_t)(row0 + row) << 8) + c8 * 8;
        else      base = (s ? em : eh) + ((size_t)(col0 + row) << 8) + c8 * 8;
        srcbase[i] = base;
        ldsoff[i] = o;
    }

    f32x4 acc[4][4];
    #pragma unroll
    for (int i = 0; i < 4; ++i)
        #pragma unroll
        for (int j = 0; j < 4; ++j) acc[i][j] = (f32x4){0.f, 0.f, 0.f, 0.f};

    for (int k0 = 0; k0 < EMB_D; k0 += 32) {
        __syncthreads();
        #pragma unroll
        for (int i = 0; i < 8; ++i)
            gload16(srcbase[i] + k0, lds + ldsoff[i]);
        __syncthreads();

        half8 ah[4], am[4], bh[4], bm[4];
        #pragma unroll
        for (int f = 0; f < 4; ++f) {
            ah[f] = *(const half8*)(lds + aoff[f]);
            am[f] = *(const half8*)(lds + (aoff[f] ^ 16));
            bh[f] = *(const half8*)(lds + boff[f]);
            bm[f] = *(const half8*)(lds + (boff[f] ^ 16));
        }
        #pragma unroll
        for (int i = 0; i < 4; ++i)
            #pragma unroll
            for (int j = 0; j < 4; ++j) {
                acc[i][j] = __builtin_amdgcn_mfma_f32_16x16x32_f16(ah[i], bh[j], acc[i][j], 0, 0, 0);
                acc[i][j] = __builtin_amdgcn_mfma_f32_16x16x32_f16(ah[i], bm[j], acc[i][j], 0, 0, 0);
                acc[i][j] = __builtin_amdgcn_mfma_f32_16x16x32_f16(am[i], bh[j], acc[i][j], 0, 0, 0);
            }
    }

    // epilogue: approx d; per (row, this wave's 64 cols) keep top-2 packed keys
    float es[4];
    #pragma unroll
    for (int j = 0; j < 4; ++j) es[j] = esq[col0 + wn * 64 + j * 16 + l15];

    #pragma unroll
    for (int i = 0; i < 4; ++i) {
        #pragma unroll
        for (int r = 0; r < 4; ++r) {
            int rl = wm * 64 + i * 16 + lq * 4 + r;
            float zs = zsq[row0 + rl];
            ull k1 = ~0ULL, k2 = ~0ULL;
            #pragma unroll
            for (int j = 0; j < 4; ++j) {
                int cg = col0 + wn * 64 + j * 16 + l15;
                float t1 = __fadd_rn(zs, es[j]);
                float d  = __fsub_rn(t1, __fmul_rn(2.0f, acc[i][j][r]));
                ull key = ((ull)__float_as_uint(d) << 32) | (unsigned)cg;
                if (key < k1) { k2 = k1; k1 = key; }
                else if (key < k2) { k2 = key; }
            }
            // merge top-2 across the 16-lane col group (same lq)
            #pragma unroll
            for (int m = 1; m < 16; m <<= 1) {
                ull o1 = __shfl_xor(k1, m, 64);
                ull o2 = __shfl_xor(k2, m, 64);
                if (o1 < k1) { k2 = (k1 < o2) ? k1 : o2; k1 = o1; }
                else         { k2 = (o1 < k2) ? o1 : k2; }
            }
            if (l15 == 0) {
                ull* p = keys2 + (((size_t)(row0 + rl)) << 5) + (cb << 2) + (wn << 1);
                p[0] = k1; p[1] = k2;
            }
        }
    }
}

// ---------------- refine: exact-fp32 final decision per row ----------------
// one wave per row; 32 candidate keys/row; fast path when runner-up > margin away
__global__ __launch_bounds__(256) void refine_rows(
        const ull* __restrict__ keys2, const float* __restrict__ z,
        const float* __restrict__ emb, const float* __restrict__ zsq,
        const float* __restrict__ esq,
        int* __restrict__ idxarr, float* __restrict__ out_idx) {
    int row = (blockIdx.x << 2) | (threadIdx.x >> 6);
    int lane = threadIdx.x & 63;

    ull k = (lane < 32) ? keys2[((size_t)row << 5) | lane] : ~0ULL;
    ull kmin = k;
    #pragma unroll
    for (int m = 1; m < 64; m <<= 1) {
        ull o = __shfl_xor(kmin, m, 64);
        kmin = o < kmin ? o : kmin;
    }

    float dmin = __uint_as_float((unsigned)(kmin >> 32));
    float dme  = __uint_as_float((unsigned)(k >> 32));
    bool cand = (lane < 32) && (dme <= __fadd_rn(dmin, 1e-4f));
    ull bal = __ballot(cand);
    int winner;
    if (__popcll(bal) == 1) {
        winner = (int)(unsigned)(kmin & 0xFFFFFFFFu);     // provably exact
    } else {
        // exact fp32 recompute for each candidate (wave-cooperative)
        const float* zp = z + ((size_t)(row >> 10) << 18) + (row & (HW - 1));
        float zr[4];
        #pragma unroll
        for (int e = 0; e < 4; ++e) zr[e] = zp[(size_t)(lane + 64 * e) << 10];
        float zs = zsq[row];
        ull bestk = ~0ULL;
        while (bal) {
            int src = __ffsll(bal) - 1;
            bal &= bal - 1;
            ull ck = __shfl(k, src, 64);
            int c = (int)(unsigned)(ck & 0xFFFFFFFFu);
            const float* ep = emb + (size_t)c * EMB_D;
            float p = __fmul_rn(zr[3], ep[lane + 192]);
            p = __builtin_fmaf(zr[2], ep[lane + 128], p);
            p = __builtin_fmaf(zr[1], ep[lane + 64], p);
            p = __builtin_fmaf(zr[0], ep[lane], p);
            #pragma unroll
            for (int m = 1; m < 64; m <<= 1)
                p = __fadd_rn(p, __shfl_xor(p, m, 64));
            float d = __fsub_rn(__fadd_rn(zs, esq[c]), __fmul_rn(2.0f, p));
            ull kk = ((ull)__float_as_uint(d) << 32) | (unsigned)c;
            bestk = kk < bestk ? kk : bestk;
        }
        winner = (int)(unsigned)(bestk & 0xFFFFFFFFu);
    }
    if (lane == 0) {
        idxarr[row] = winner;
        out_idx[row] = (float)winner;
    }
}

// ---------------- fused one-hot writer + histogram ----------------
__global__ void onehot_rows(const int* __restrict__ idxarr,
                            float* __restrict__ nearest, int* __restrict__ hist) {
    int row = blockIdx.x;
    int t = threadIdx.x;
    int idx = idxarr[row];
    int base = t << 2;
    float2 v0 = { idx == base     ? 1.f : 0.f, idx == base + 1 ? 1.f : 0.f };
    float2 v1 = { idx == base + 2 ? 1.f : 0.f, idx == base + 3 ? 1.f : 0.f };
    float2* p = (float2*)(nearest + ((size_t)row << 10)) + (t << 1);
    p[0] = v0;
    p[1] = v1;
    if (t == 0) atomicAdd(&hist[idx], 1);
}

// ---------------- zq gather + straight-through output + loss partials ----------------
__global__ void zq_loss_kernel(const float* __restrict__ z, const float* __restrict__ emb,
                               const int* __restrict__ idxarr, float* __restrict__ outzq,
                               double* __restrict__ lossp) {
    int o = blockIdx.x * 256 + threadIdx.x;
    int hw = o & (HW - 1);
    int c  = (o >> 10) & 255;
    int b  = o >> 18;
    int n  = (b << 10) | hw;
    int idx = idxarr[n];
    float zc = z[o];
    float zq = emb[idx * EMB_D + c];
    float diff = __fsub_rn(zq, zc);
    outzq[o] = __fadd_rn(zc, diff);
    float sq = __fmul_rn(diff, diff);

    __shared__ double sd[256];
    sd[threadIdx.x] = (double)sq;
    __syncthreads();
    for (int s = 128; s > 0; s >>= 1) {
        if (threadIdx.x < s) sd[threadIdx.x] += sd[threadIdx.x + s];
        __syncthreads();
    }
    if (threadIdx.x == 0) lossp[blockIdx.x] = sd[0];
}

// ---------------- scalars ----------------
__global__ void finalize_scalars(const double* __restrict__ lossp,
                                 const int* __restrict__ hist,
                                 float* __restrict__ out_loss,
                                 float* __restrict__ out_perp) {
    __shared__ double sd[1024];
    int t = threadIdx.x;

    double s = 0.0;
    for (int i = 0; i < 32; ++i) s += lossp[t + (i << 10)];
    sd[t] = s;
    __syncthreads();
    for (int st = 512; st > 0; st >>= 1) {
        if (t < st) sd[t] += sd[t + st];
        __syncthreads();
    }
    if (t == 0) {
        double loss = 1.25 * (sd[0] / 8388608.0);
        *out_loss = (float)loss;
    }
    __syncthreads();

    float p = (float)hist[t] * (1.0f / 32768.0f);
    float term = __fmul_rn(p, logf(__fadd_rn(p, 1e-10f)));
    sd[t] = (double)term;
    __syncthreads();
    for (int st = 512; st > 0; st >>= 1) {
        if (t < st) sd[t] += sd[t + st];
        __syncthreads();
    }
    if (t == 0) *out_perp = expf(-(float)sd[0]);
}

// ---------------- launch ----------------
extern "C" void kernel_launch(void* const* d_in, const int* in_sizes, int n_in,
                              void* d_out, int out_size, void* d_ws, size_t ws_size,
                              hipStream_t stream) {
    const float* z   = (const float*)d_in[0];
    const float* emb = (const float*)d_in[1];
    float* out = (float*)d_out;
    char*  ws  = (char*)d_ws;

    int*     idxarr = (int*)(ws + WS_IDX);
    int*     hist   = (int*)(ws + WS_HIST);
    float*   zsq    = (float*)(ws + WS_ZSQ);
    float*   esq    = (float*)(ws + WS_ESQ);
    double*  lossp  = (double*)(ws + WS_LOSSP);
    _Float16* eh    = (_Float16*)(ws + WS_EH);
    _Float16* em    = (_Float16*)(ws + WS_EM);

    // scratch inside the (not-yet-written) one-hot output region
    _Float16* zh    = (_Float16*)((char*)d_out + ZH_BYTE_OFF);
    _Float16* zm    = (_Float16*)((char*)d_out + ZM_BYTE_OFF);
    ull*      keys2 = (ull*)((char*)d_out + K2_BYTE_OFF);

    hipMemsetAsync(hist, 0, (size_t)N_EMB * 4, stream);

    split_z<<<512, 256, 0, stream>>>(z, zh, zm);
    split_e<<<N_EMB, 256, 0, stream>>>(emb, eh, em);
    esq_kernel<<<N_EMB / 256, 256, 0, stream>>>(emb, esq);
    zsq_kernel<<<N_ROWS / 256, 256, 0, stream>>>(z, zsq);

    gemm_mfma_argmin<<<(N_ROWS / 128) * (N_EMB / 128), 256, 0, stream>>>(
        zh, zm, eh, em, zsq, esq, keys2);

    refine_rows<<<N_ROWS / 4, 256, 0, stream>>>(keys2, z, emb, zsq, esq,
                                                idxarr, out + OUT_IDX);
    onehot_rows<<<N_ROWS, 256, 0, stream>>>(idxarr, out + OUT_NEAREST, hist);
    zq_loss_kernel<<<8388608 / 256, 256, 0, stream>>>(z, emb, idxarr, out, lossp);
    finalize_scalars<<<1, 1024, 0, stream>>>(lossp, hist,
                                             out + OUT_LOSS, out + OUT_PERP);
}

// Round 4
// 210.981 us; speedup vs baseline: 1.5211x; 1.2042x over previous
//
#include <hip/hip_runtime.h>

// ---------------- problem constants ----------------
#define N_ROWS 32768       // 32*32*32 spatial positions
#define N_EMB  1024
#define EMB_D  256
#define HW     1024        // 32*32

// d_out layout (floats)
#define OUT_ZQ      0
#define OUT_LOSS    8388608
#define OUT_PERP    8388609
#define OUT_NEAREST 8388610
#define OUT_IDX     41943042

// scratch inside the one-hot output region (consumed before onehot_rows overwrites)
#define ZH_BYTE_OFF   33554448ULL
#define ZM_BYTE_OFF   (ZH_BYTE_OFF + 16777216ULL)   // 50331664
#define K2_BYTE_OFF   (ZM_BYTE_OFF + 16777216ULL)   // 67108880, keys2: 32768*32*8 = 8 MB

// ws layout (bytes)
#define WS_IDX    0          // 32768 * 4
#define WS_HIST   131072     // 1024 * 4
#define WS_ZSQ    135168     // 32768 * 4
#define WS_ESQ    266240     // 1024 * 4
#define WS_LOSSP  270336     // 8192 * 8
#define WS_EH     532480     // 1024*256*2
#define WS_EM     1056768    // 1024*256*2
#define WS_TOTAL  1581056

typedef unsigned long long ull;
typedef _Float16 half8 __attribute__((ext_vector_type(8)));
typedef float f32x4 __attribute__((ext_vector_type(4)));

__device__ __forceinline__ void gload16(const void* g, void* l) {
    __builtin_amdgcn_global_load_lds(
        (const __attribute__((address_space(1))) unsigned int*)g,
        (__attribute__((address_space(3))) unsigned int*)l, 16, 0, 0);
}

__device__ __forceinline__ float pairwise8_combine(const float r[8]) {
    return __fadd_rn(__fadd_rn(__fadd_rn(r[0], r[1]), __fadd_rn(r[2], r[3])),
                     __fadd_rn(__fadd_rn(r[4], r[5]), __fadd_rn(r[6], r[7])));
}

// ---------------- fp16 split of z (transpose to [n][k]) + fused zsq ----------------
// grid 256, block 256: n = bid*128 + (tid&127); half = tid>>7 covers c in [half*128,+128)
// zsq = fadd(tot0, tot1), each tot = numpy 8-acc pairwise fold over its 128 -> exact
__global__ void split_z(const float* __restrict__ z,
                        _Float16* __restrict__ zh, _Float16* __restrict__ zm,
                        float* __restrict__ zsq) {
    __shared__ float lhalf[2][128];
    int tid = threadIdx.x;
    int nl = tid & 127, h = tid >> 7;
    int n = blockIdx.x * 128 + nl;
    int b = n >> 10, hw = n & (HW - 1);
    const float* zp = z + ((size_t)b << 18) + hw;
    int cbeg = h << 7;

    float r[8];
    {   // c0 = 0 chunk (init accumulators)
        half8 hv, mv;
        #pragma unroll
        for (int e = 0; e < 8; ++e) {
            float x = zp[(size_t)(cbeg + e) << 10];
            _Float16 hf = (_Float16)x;
            _Float16 mf = (_Float16)(x - (float)hf);
            hv[e] = hf; mv[e] = mf;
            r[e] = __fmul_rn(x, x);
        }
        *(half8*)(zh + ((size_t)n << 8) + cbeg) = hv;
        *(half8*)(zm + ((size_t)n << 8) + cbeg) = mv;
    }
    for (int c0 = 8; c0 < 128; c0 += 8) {
        half8 hv, mv;
        #pragma unroll
        for (int e = 0; e < 8; ++e) {
            float x = zp[(size_t)(cbeg + c0 + e) << 10];
            _Float16 hf = (_Float16)x;
            _Float16 mf = (_Float16)(x - (float)hf);
            hv[e] = hf; mv[e] = mf;
            r[e] = __fadd_rn(r[e], __fmul_rn(x, x));
        }
        *(half8*)(zh + ((size_t)n << 8) + cbeg + c0) = hv;
        *(half8*)(zm + ((size_t)n << 8) + cbeg + c0) = mv;
    }
    lhalf[h][nl] = pairwise8_combine(r);
    __syncthreads();
    if (h == 0) zsq[n] = __fadd_rn(lhalf[0][nl], lhalf[1][nl]);
}

// ---------------- fp16 split of emb ----------------
__global__ void split_e(const float* __restrict__ emb,
                        _Float16* __restrict__ eh, _Float16* __restrict__ em) {
    int c = blockIdx.x;
    int k = threadIdx.x;
    float x = emb[c * EMB_D + k];
    _Float16 h = (_Float16)x;
    _Float16 m = (_Float16)(x - (float)h);
    eh[c * EMB_D + k] = h;
    em[c * EMB_D + k] = m;
}

// ---------------- esq (numpy pairwise) + hist zeroing ----------------
__global__ void esq_kernel(const float* __restrict__ emb, float* __restrict__ esq,
                           int* __restrict__ hist) {
    int c = blockIdx.x * 256 + threadIdx.x;
    const float* p = emb + (size_t)c * EMB_D;
    float tot[2];
    #pragma unroll
    for (int h = 0; h < 2; ++h) {
        float r[8];
        #pragma unroll
        for (int i = 0; i < 8; ++i) {
            float x = p[h * 128 + i];
            r[i] = __fmul_rn(x, x);
        }
        for (int k = 8; k < 128; k += 8) {
            #pragma unroll
            for (int i = 0; i < 8; ++i) {
                float x = p[h * 128 + k + i];
                r[i] = __fadd_rn(r[i], __fmul_rn(x, x));
            }
        }
        tot[h] = pairwise8_combine(r);
    }
    esq[c] = __fadd_rn(tot[0], tot[1]);
    hist[c] = 0;
}

// ---------------- MFMA distance GEMM + per-(row,64col) top-2 keys ----------------
// grid 2048; XCD-aware remap so the 8 cb-siblings of one rb share an XCD's L2.
// 256 threads = 4 waves (2x2), wave tile 64x64. LDS double-buffered 2 x 32KB:
// stage(t+1) issued right after the barrier, latency hidden under tile-t compute.
__global__ __launch_bounds__(256) void gemm_mfma_argmin(
        const _Float16* __restrict__ zh, const _Float16* __restrict__ zm,
        const _Float16* __restrict__ eh, const _Float16* __restrict__ em,
        const float* __restrict__ zsq, const float* __restrict__ esq,
        ull* __restrict__ keys2) {
    __shared__ __align__(16) char lds[65536];   // buf0 [0,32K): A 16K + B 16K; buf1 [32K,64K)

    int t = threadIdx.x;
    int bid = blockIdx.x;
    // bijective remap: rb from bits {0-2,6-10}, cb from bits {3-5}
    int rb = ((bid & 7) << 5) | (bid >> 6);
    int cb = (bid >> 3) & 7;
    int row0 = rb << 7, col0 = cb << 7;
    int lane = t & 63, wave = t >> 6;
    int wm = wave >> 1, wn = wave & 1;
    int l15 = lane & 15, lq = lane >> 4;

    // k0-invariant LDS read offsets (h; m = ^16), XOR-swizzled rows
    int aoff[4], boff[4];
    #pragma unroll
    for (int f = 0; f < 4; ++f) {
        int r = wm * 64 + f * 16 + l15;
        aoff[f] = r * 128 + ((lq * 32) ^ ((r & 7) << 4));
        int c = wn * 64 + f * 16 + l15;
        boff[f] = 16384 + c * 128 + ((lq * 32) ^ ((c & 7) << 4));
    }

    // staging: 8 issues x 256 threads x 16B = 32KB; inverse-swizzled global source
    const _Float16* srcbase[8];
    int ldsoff[8];
    #pragma unroll
    for (int i = 0; i < 8; ++i) {
        int o = i * 4096 + t * 16;
        int isB = o >> 14;
        int ol = o & 16383;
        int row = ol >> 7;
        int raw = (ol & 127) ^ ((row & 7) << 4);
        int c8 = raw >> 5, s = (raw >> 4) & 1;
        const _Float16* base;
        if (!isB) base = (s ? zm : zh) + ((size_t)(row0 + row) << 8) + c8 * 8;
        else      base = (s ? em : eh) + ((size_t)(col0 + row) << 8) + c8 * 8;
        srcbase[i] = base;
        ldsoff[i] = o;
    }

    f32x4 acc[4][4];
    #pragma unroll
    for (int i = 0; i < 4; ++i)
        #pragma unroll
        for (int j = 0; j < 4; ++j) acc[i][j] = (f32x4){0.f, 0.f, 0.f, 0.f};

    // prologue: stage tile 0 into buf0
    #pragma unroll
    for (int i = 0; i < 8; ++i)
        gload16(srcbase[i], lds + ldsoff[i]);

    #pragma unroll
    for (int t8 = 0; t8 < 8; ++t8) {
        __syncthreads();                       // drains stage(t8); releases buf[t8^1]
        if (t8 < 7) {                          // issue stage(t8+1) into other buffer
            const int nb = ((t8 + 1) & 1) << 15;
            #pragma unroll
            for (int i = 0; i < 8; ++i)
                gload16(srcbase[i] + (t8 + 1) * 32, lds + nb + ldsoff[i]);
        }
        const int cbuf = (t8 & 1) << 15;

        half8 ah[4], am[4], bh[4], bm[4];
        #pragma unroll
        for (int f = 0; f < 4; ++f) {
            ah[f] = *(const half8*)(lds + cbuf + aoff[f]);
            am[f] = *(const half8*)(lds + cbuf + (aoff[f] ^ 16));
            bh[f] = *(const half8*)(lds + cbuf + boff[f]);
            bm[f] = *(const half8*)(lds + cbuf + (boff[f] ^ 16));
        }
        #pragma unroll
        for (int i = 0; i < 4; ++i)
            #pragma unroll
            for (int j = 0; j < 4; ++j) {
                acc[i][j] = __builtin_amdgcn_mfma_f32_16x16x32_f16(ah[i], bh[j], acc[i][j], 0, 0, 0);
                acc[i][j] = __builtin_amdgcn_mfma_f32_16x16x32_f16(ah[i], bm[j], acc[i][j], 0, 0, 0);
                acc[i][j] = __builtin_amdgcn_mfma_f32_16x16x32_f16(am[i], bh[j], acc[i][j], 0, 0, 0);
            }
    }

    // epilogue: approx d; per (row, this wave's 64 cols) keep top-2 packed keys
    float es[4];
    #pragma unroll
    for (int j = 0; j < 4; ++j) es[j] = esq[col0 + wn * 64 + j * 16 + l15];

    #pragma unroll
    for (int i = 0; i < 4; ++i) {
        #pragma unroll
        for (int r = 0; r < 4; ++r) {
            int rl = wm * 64 + i * 16 + lq * 4 + r;
            float zs = zsq[row0 + rl];
            ull k1 = ~0ULL, k2 = ~0ULL;
            #pragma unroll
            for (int j = 0; j < 4; ++j) {
                int cg = col0 + wn * 64 + j * 16 + l15;
                float t1 = __fadd_rn(zs, es[j]);
                float d  = __fsub_rn(t1, __fmul_rn(2.0f, acc[i][j][r]));
                ull key = ((ull)__float_as_uint(d) << 32) | (unsigned)cg;
                if (key < k1) { k2 = k1; k1 = key; }
                else if (key < k2) { k2 = key; }
            }
            #pragma unroll
            for (int m = 1; m < 16; m <<= 1) {
                ull o1 = __shfl_xor(k1, m, 64);
                ull o2 = __shfl_xor(k2, m, 64);
                if (o1 < k1) { k2 = (k1 < o2) ? k1 : o2; k1 = o1; }
                else         { k2 = (o1 < k2) ? o1 : k2; }
            }
            if (l15 == 0) {
                ull* p = keys2 + (((size_t)(row0 + rl)) << 5) + (cb << 2) + (wn << 1);
                p[0] = k1; p[1] = k2;
            }
        }
    }
}

// ---------------- refine: exact-fp32 final decision per row + histogram ----------------
__global__ __launch_bounds__(256) void refine_rows(
        const ull* __restrict__ keys2, const float* __restrict__ z,
        const float* __restrict__ emb, const float* __restrict__ zsq,
        const float* __restrict__ esq,
        int* __restrict__ idxarr, float* __restrict__ out_idx,
        int* __restrict__ hist) {
    int row = (blockIdx.x << 2) | (threadIdx.x >> 6);
    int lane = threadIdx.x & 63;

    ull k = (lane < 32) ? keys2[((size_t)row << 5) | lane] : ~0ULL;
    ull kmin = k;
    #pragma unroll
    for (int m = 1; m < 64; m <<= 1) {
        ull o = __shfl_xor(kmin, m, 64);
        kmin = o < kmin ? o : kmin;
    }

    float dmin = __uint_as_float((unsigned)(kmin >> 32));
    float dme  = __uint_as_float((unsigned)(k >> 32));
    bool cand = (lane < 32) && (dme <= __fadd_rn(dmin, 1e-4f));
    ull bal = __ballot(cand);
    int winner;
    if (__popcll(bal) == 1) {
        winner = (int)(unsigned)(kmin & 0xFFFFFFFFu);     // provably exact
    } else {
        // exact fp32 recompute for each candidate (wave-cooperative)
        const float* zp = z + ((size_t)(row >> 10) << 18) + (row & (HW - 1));
        float zr[4];
        #pragma unroll
        for (int e = 0; e < 4; ++e) zr[e] = zp[(size_t)(lane + 64 * e) << 10];
        float zs = zsq[row];
        ull bestk = ~0ULL;
        while (bal) {
            int src = __ffsll(bal) - 1;
            bal &= bal - 1;
            ull ck = __shfl(k, src, 64);
            int c = (int)(unsigned)(ck & 0xFFFFFFFFu);
            const float* ep = emb + (size_t)c * EMB_D;
            float p = __fmul_rn(zr[3], ep[lane + 192]);
            p = __builtin_fmaf(zr[2], ep[lane + 128], p);
            p = __builtin_fmaf(zr[1], ep[lane + 64], p);
            p = __builtin_fmaf(zr[0], ep[lane], p);
            #pragma unroll
            for (int m = 1; m < 64; m <<= 1)
                p = __fadd_rn(p, __shfl_xor(p, m, 64));
            float d = __fsub_rn(__fadd_rn(zs, esq[c]), __fmul_rn(2.0f, p));
            ull kk = ((ull)__float_as_uint(d) << 32) | (unsigned)c;
            bestk = kk < bestk ? kk : bestk;
        }
        winner = (int)(unsigned)(bestk & 0xFFFFFFFFu);
    }
    if (lane == 0) {
        idxarr[row] = winner;
        out_idx[row] = (float)winner;
        atomicAdd(&hist[winner], 1);
    }
}

// ---------------- one-hot writer (float4 stores) ----------------
__global__ void onehot_rows(const int* __restrict__ idxarr,
                            float* __restrict__ nearest) {
    int row = blockIdx.x;
    int t = threadIdx.x;
    int idx = idxarr[row];
    int base = t << 2;
    float4 v = { idx == base     ? 1.f : 0.f, idx == base + 1 ? 1.f : 0.f,
                 idx == base + 2 ? 1.f : 0.f, idx == base + 3 ? 1.f : 0.f };
    ((float4*)(nearest + ((size_t)row << 10)))[t] = v;
}

// ---------------- zq gather + straight-through output + loss partials (x4 vec) ----
__global__ void zq_loss_kernel(const float* __restrict__ z, const float* __restrict__ emb,
                               const int* __restrict__ idxarr, float* __restrict__ outzq,
                               double* __restrict__ lossp) {
    int o0 = (blockIdx.x * 256 + threadIdx.x) << 2;   // NCHW flat, 4 consecutive (same c)
    int hw = o0 & (HW - 1);
    int c  = (o0 >> 10) & 255;
    int b  = o0 >> 18;
    int n0 = (b << 10) | hw;
    int4  idx = *(const int4*)(idxarr + n0);
    float4 zc = *(const float4*)(z + o0);

    float4 zq = { emb[idx.x * EMB_D + c], emb[idx.y * EMB_D + c],
                  emb[idx.z * EMB_D + c], emb[idx.w * EMB_D + c] };
    float4 d  = { __fsub_rn(zq.x, zc.x), __fsub_rn(zq.y, zc.y),
                  __fsub_rn(zq.z, zc.z), __fsub_rn(zq.w, zc.w) };
    float4 st = { __fadd_rn(zc.x, d.x), __fadd_rn(zc.y, d.y),
                  __fadd_rn(zc.z, d.z), __fadd_rn(zc.w, d.w) };
    *(float4*)(outzq + o0) = st;

    double s = (double)__fmul_rn(d.x, d.x) + (double)__fmul_rn(d.y, d.y)
             + (double)__fmul_rn(d.z, d.z) + (double)__fmul_rn(d.w, d.w);
    __shared__ double sd[256];
    sd[threadIdx.x] = s;
    __syncthreads();
    for (int st2 = 128; st2 > 0; st2 >>= 1) {
        if (threadIdx.x < st2) sd[threadIdx.x] += sd[threadIdx.x + st2];
        __syncthreads();
    }
    if (threadIdx.x == 0) lossp[blockIdx.x] = sd[0];
}

// ---------------- scalars ----------------
__global__ void finalize_scalars(const double* __restrict__ lossp,
                                 const int* __restrict__ hist,
                                 float* __restrict__ out_loss,
                                 float* __restrict__ out_perp) {
    __shared__ double sd[1024];
    int t = threadIdx.x;

    double s = 0.0;
    for (int i = 0; i < 8; ++i) s += lossp[t + (i << 10)];
    sd[t] = s;
    __syncthreads();
    for (int st = 512; st > 0; st >>= 1) {
        if (t < st) sd[t] += sd[t + st];
        __syncthreads();
    }
    if (t == 0) {
        double loss = 1.25 * (sd[0] / 8388608.0);
        *out_loss = (float)loss;
    }
    __syncthreads();

    float p = (float)hist[t] * (1.0f / 32768.0f);
    float term = __fmul_rn(p, logf(__fadd_rn(p, 1e-10f)));
    sd[t] = (double)term;
    __syncthreads();
    for (int st = 512; st > 0; st >>= 1) {
        if (t < st) sd[t] += sd[t + st];
        __syncthreads();
    }
    if (t == 0) *out_perp = expf(-(float)sd[0]);
}

// ---------------- launch ----------------
extern "C" void kernel_launch(void* const* d_in, const int* in_sizes, int n_in,
                              void* d_out, int out_size, void* d_ws, size_t ws_size,
                              hipStream_t stream) {
    const float* z   = (const float*)d_in[0];
    const float* emb = (const float*)d_in[1];
    float* out = (float*)d_out;
    char*  ws  = (char*)d_ws;

    int*     idxarr = (int*)(ws + WS_IDX);
    int*     hist   = (int*)(ws + WS_HIST);
    float*   zsq    = (float*)(ws + WS_ZSQ);
    float*   esq    = (float*)(ws + WS_ESQ);
    double*  lossp  = (double*)(ws + WS_LOSSP);
    _Float16* eh    = (_Float16*)(ws + WS_EH);
    _Float16* em    = (_Float16*)(ws + WS_EM);

    // scratch inside the (not-yet-written) one-hot output region
    _Float16* zh    = (_Float16*)((char*)d_out + ZH_BYTE_OFF);
    _Float16* zm    = (_Float16*)((char*)d_out + ZM_BYTE_OFF);
    ull*      keys2 = (ull*)((char*)d_out + K2_BYTE_OFF);

    split_z<<<256, 256, 0, stream>>>(z, zh, zm, zsq);
    split_e<<<N_EMB, 256, 0, stream>>>(emb, eh, em);
    esq_kernel<<<N_EMB / 256, 256, 0, stream>>>(emb, esq, hist);

    gemm_mfma_argmin<<<(N_ROWS / 128) * (N_EMB / 128), 256, 0, stream>>>(
        zh, zm, eh, em, zsq, esq, keys2);

    refine_rows<<<N_ROWS / 4, 256, 0, stream>>>(keys2, z, emb, zsq, esq,
                                                idxarr, out + OUT_IDX, hist);
    onehot_rows<<<N_ROWS, 256, 0, stream>>>(idxarr, out + OUT_NEAREST);
    zq_loss_kernel<<<8388608 / 1024, 256, 0, stream>>>(z, emb, idxarr, out, lossp);
    finalize_scalars<<<1, 1024, 0, stream>>>(lossp, hist,
                                             out + OUT_LOSS, out + OUT_PERP);
}

// Round 5
// 146.388 us; speedup vs baseline: 2.1923x; 1.4412x over previous
//
#include <hip/hip_runtime.h>

// ---------------- problem constants ----------------
#define N_ROWS 32768       // 32*32*32 spatial positions
#define N_EMB  1024
#define EMB_D  256
#define HW     1024        // 32*32

// d_out layout (floats)
#define OUT_ZQ      0
#define OUT_LOSS    8388608
#define OUT_PERP    8388609
#define OUT_NEAREST 8388610
#define OUT_IDX     41943042

// scratch placement inside d_out (stream-ordered reuse):
//  keys2 [0, 8MB)          in the zq region  — written by gemm, read by refine,
//                            overwritten by zq_loss afterwards
//  zh    [33.5MB+16, +16.7MB) in the one-hot region — written by split_z, read by
//                            gemm, overwritten by refine's one-hot stores afterwards
#define ZH_BYTE_OFF   33554448ULL

// ws layout (bytes)
#define WS_IDX    0          // 32768 * 4
#define WS_HIST   131072     // 1024 * 4
#define WS_ZSQ    135168     // 32768 * 4
#define WS_ESQ    266240     // 1024 * 4
#define WS_LOSSP  270336     // 8192 * 8
#define WS_EH     532480     // 1024*256*2
#define WS_TOTAL  1056768

typedef unsigned long long ull;
typedef _Float16 half8 __attribute__((ext_vector_type(8)));
typedef float f32x4 __attribute__((ext_vector_type(4)));

__device__ __forceinline__ void gload16(const void* g, void* l) {
    __builtin_amdgcn_global_load_lds(
        (const __attribute__((address_space(1))) unsigned int*)g,
        (__attribute__((address_space(3))) unsigned int*)l, 16, 0, 0);
}

__device__ __forceinline__ float pairwise8_combine(const float r[8]) {
    return __fadd_rn(__fadd_rn(__fadd_rn(r[0], r[1]), __fadd_rn(r[2], r[3])),
                     __fadd_rn(__fadd_rn(r[4], r[5]), __fadd_rn(r[6], r[7])));
}

// ---------------- fp16 h-part of z (transpose to [n][k]) + fused zsq ----------------
// grid 256, block 256: n = bid*128 + (tid&127); half = tid>>7 covers c in [half*128,+128)
__global__ void split_z(const float* __restrict__ z,
                        _Float16* __restrict__ zh, float* __restrict__ zsq) {
    __shared__ float lhalf[2][128];
    int tid = threadIdx.x;
    int nl = tid & 127, h = tid >> 7;
    int n = blockIdx.x * 128 + nl;
    int b = n >> 10, hw = n & (HW - 1);
    const float* zp = z + ((size_t)b << 18) + hw;
    int cbeg = h << 7;

    float r[8];
    {   // c0 = 0 chunk (init accumulators)
        half8 hv;
        #pragma unroll
        for (int e = 0; e < 8; ++e) {
            float x = zp[(size_t)(cbeg + e) << 10];
            hv[e] = (_Float16)x;
            r[e] = __fmul_rn(x, x);
        }
        *(half8*)(zh + ((size_t)n << 8) + cbeg) = hv;
    }
    for (int c0 = 8; c0 < 128; c0 += 8) {
        half8 hv;
        #pragma unroll
        for (int e = 0; e < 8; ++e) {
            float x = zp[(size_t)(cbeg + c0 + e) << 10];
            hv[e] = (_Float16)x;
            r[e] = __fadd_rn(r[e], __fmul_rn(x, x));
        }
        *(half8*)(zh + ((size_t)n << 8) + cbeg + c0) = hv;
    }
    lhalf[h][nl] = pairwise8_combine(r);
    __syncthreads();
    if (h == 0) zsq[n] = __fadd_rn(lhalf[0][nl], lhalf[1][nl]);
}

// ---------------- fp16 h-part of emb ----------------
__global__ void split_e(const float* __restrict__ emb, _Float16* __restrict__ eh) {
    int c = blockIdx.x;
    int k = threadIdx.x;
    eh[c * EMB_D + k] = (_Float16)emb[c * EMB_D + k];
}

// ---------------- esq (numpy pairwise) + hist zeroing ----------------
__global__ void esq_kernel(const float* __restrict__ emb, float* __restrict__ esq,
                           int* __restrict__ hist) {
    int c = blockIdx.x * 256 + threadIdx.x;
    const float* p = emb + (size_t)c * EMB_D;
    float tot[2];
    #pragma unroll
    for (int h = 0; h < 2; ++h) {
        float r[8];
        #pragma unroll
        for (int i = 0; i < 8; ++i) {
            float x = p[h * 128 + i];
            r[i] = __fmul_rn(x, x);
        }
        for (int k = 8; k < 128; k += 8) {
            #pragma unroll
            for (int i = 0; i < 8; ++i) {
                float x = p[h * 128 + k + i];
                r[i] = __fadd_rn(r[i], __fmul_rn(x, x));
            }
        }
        tot[h] = pairwise8_combine(r);
    }
    esq[c] = __fadd_rn(tot[0], tot[1]);
    hist[c] = 0;
}

// ---------------- MFMA distance GEMM (hh-only) + per-(row,64col) top-2 keys ----------
// grid 2048; XCD remap so the 8 cb-siblings of one rb share an XCD's L2.
// 256 threads = 4 waves (2x2), wave tile 64x64. BK=64: 4 K-iters, single-buffer
// 32KB LDS, round-3-proven 2-barrier structure (no explicit dbuf: compiler can't
// disambiguate LDS aliasing and would insert vmcnt(0) anyway).
__global__ __launch_bounds__(256) void gemm_mfma_argmin(
        const _Float16* __restrict__ zh, const _Float16* __restrict__ eh,
        const float* __restrict__ zsq, const float* __restrict__ esq,
        ull* __restrict__ keys2) {
    __shared__ __align__(16) char lds[32768];   // A [0,16K): 128 rows x 128B; B [16K,32K)

    int t = threadIdx.x;
    int bid = blockIdx.x;
    // bijective remap: rb from bits {0-2,6-10}, cb from bits {3-5}
    int rb = ((bid & 7) << 5) | (bid >> 6);
    int cb = (bid >> 3) & 7;
    int row0 = rb << 7, col0 = cb << 7;
    int lane = t & 63, wave = t >> 6;
    int wm = wave >> 1, wn = wave & 1;
    int l15 = lane & 15, lq = lane >> 4;

    // read offsets: frag f (row group), k-chunk kc (K=32 each); XOR-swizzled rows
    int aoff[4][2], boff[4][2];
    #pragma unroll
    for (int f = 0; f < 4; ++f) {
        int r = wm * 64 + f * 16 + l15;
        int c = wn * 64 + f * 16 + l15;
        #pragma unroll
        for (int kc = 0; kc < 2; ++kc) {
            aoff[f][kc] = r * 128 + ((kc * 64 + lq * 16) ^ ((r & 7) << 4));
            boff[f][kc] = 16384 + c * 128 + ((kc * 64 + lq * 16) ^ ((c & 7) << 4));
        }
    }

    // staging: 8 issues x 256 threads x 16B = 32KB; inverse-swizzled global source
    const _Float16* srcbase[8];
    int ldsoff[8];
    #pragma unroll
    for (int i = 0; i < 8; ++i) {
        int o = i * 4096 + t * 16;
        int isB = o >> 14;
        int ol = o & 16383;
        int row = ol >> 7;
        int raw = (ol & 127) ^ ((row & 7) << 4);   // logical byte within row
        srcbase[i] = (isB ? eh + ((size_t)(col0 + row) << 8)
                          : zh + ((size_t)(row0 + row) << 8)) + (raw >> 1);
        ldsoff[i] = o;
    }

    f32x4 acc[4][4];
    #pragma unroll
    for (int i = 0; i < 4; ++i)
        #pragma unroll
        for (int j = 0; j < 4; ++j) acc[i][j] = (f32x4){0.f, 0.f, 0.f, 0.f};

    for (int t4 = 0; t4 < 4; ++t4) {
        __syncthreads();                       // previous tile fully consumed
        #pragma unroll
        for (int i = 0; i < 8; ++i)
            gload16(srcbase[i] + t4 * 64, lds + ldsoff[i]);
        __syncthreads();                       // vmcnt(0) drained before barrier

        half8 a[4][2], b[4][2];
        #pragma unroll
        for (int f = 0; f < 4; ++f) {
            a[f][0] = *(const half8*)(lds + aoff[f][0]);
            a[f][1] = *(const half8*)(lds + aoff[f][1]);
            b[f][0] = *(const half8*)(lds + boff[f][0]);
            b[f][1] = *(const half8*)(lds + boff[f][1]);
        }
        #pragma unroll
        for (int i = 0; i < 4; ++i)
            #pragma unroll
            for (int j = 0; j < 4; ++j) {
                acc[i][j] = __builtin_amdgcn_mfma_f32_16x16x32_f16(a[i][0], b[j][0], acc[i][j], 0, 0, 0);
                acc[i][j] = __builtin_amdgcn_mfma_f32_16x16x32_f16(a[i][1], b[j][1], acc[i][j], 0, 0, 0);
            }
    }

    // epilogue: approx d = fl(fl(zs+es) - fl(2*dot)); per (row, wave's 64 cols) top-2
    float es[4];
    #pragma unroll
    for (int j = 0; j < 4; ++j) es[j] = esq[col0 + wn * 64 + j * 16 + l15];

    #pragma unroll
    for (int i = 0; i < 4; ++i) {
        #pragma unroll
        for (int r = 0; r < 4; ++r) {
            int rl = wm * 64 + i * 16 + lq * 4 + r;
            float zs = zsq[row0 + rl];
            ull k1 = ~0ULL, k2 = ~0ULL;
            #pragma unroll
            for (int j = 0; j < 4; ++j) {
                int cg = col0 + wn * 64 + j * 16 + l15;
                float t1 = __fadd_rn(zs, es[j]);
                float d  = __fsub_rn(t1, __fmul_rn(2.0f, acc[i][j][r]));
                ull key = ((ull)__float_as_uint(d) << 32) | (unsigned)cg;
                if (key < k1) { k2 = k1; k1 = key; }
                else if (key < k2) { k2 = key; }
            }
            #pragma unroll
            for (int m = 1; m < 16; m <<= 1) {
                ull o1 = __shfl_xor(k1, m, 64);
                ull o2 = __shfl_xor(k2, m, 64);
                if (o1 < k1) { k2 = (k1 < o2) ? k1 : o2; k1 = o1; }
                else         { k2 = (o1 < k2) ? o1 : k2; }
            }
            if (l15 == 0) {
                ull* p = keys2 + (((size_t)(row0 + rl)) << 5) + (cb << 2) + (wn << 1);
                p[0] = k1; p[1] = k2;
            }
        }
    }
}

// ---------------- refine: exact-fp32 decision + one-hot + idx + histogram ----------
// one wave per row; 32 candidate keys; fast path when runner-up > 2e-4 away
__global__ __launch_bounds__(256) void refine_rows(
        const ull* __restrict__ keys2, const float* __restrict__ z,
        const float* __restrict__ emb, const float* __restrict__ zsq,
        const float* __restrict__ esq,
        int* __restrict__ idxarr, float* __restrict__ out_idx,
        float* __restrict__ nearest, int* __restrict__ hist) {
    int row = (blockIdx.x << 2) | (threadIdx.x >> 6);
    int lane = threadIdx.x & 63;

    ull k = (lane < 32) ? keys2[((size_t)row << 5) | lane] : ~0ULL;
    ull kmin = k;
    #pragma unroll
    for (int m = 1; m < 64; m <<= 1) {
        ull o = __shfl_xor(kmin, m, 64);
        kmin = o < kmin ? o : kmin;
    }

    float dmin = __uint_as_float((unsigned)(kmin >> 32));
    float dme  = __uint_as_float((unsigned)(k >> 32));
    bool cand = (lane < 32) && (dme <= __fadd_rn(dmin, 2e-4f));
    ull bal = __ballot(cand);
    int winner;
    if (__popcll(bal) == 1) {
        winner = (int)(unsigned)(kmin & 0xFFFFFFFFu);     // provably exact
    } else {
        // exact fp32 recompute for each candidate (wave-cooperative)
        const float* zp = z + ((size_t)(row >> 10) << 18) + (row & (HW - 1));
        float zr[4];
        #pragma unroll
        for (int e = 0; e < 4; ++e) zr[e] = zp[(size_t)(lane + 64 * e) << 10];
        float zs = zsq[row];
        ull bestk = ~0ULL;
        while (bal) {
            int src = __ffsll(bal) - 1;
            bal &= bal - 1;
            ull ck = __shfl(k, src, 64);
            int c = (int)(unsigned)(ck & 0xFFFFFFFFu);
            const float* ep = emb + (size_t)c * EMB_D;
            float p = __fmul_rn(zr[3], ep[lane + 192]);
            p = __builtin_fmaf(zr[2], ep[lane + 128], p);
            p = __builtin_fmaf(zr[1], ep[lane + 64], p);
            p = __builtin_fmaf(zr[0], ep[lane], p);
            #pragma unroll
            for (int m = 1; m < 64; m <<= 1)
                p = __fadd_rn(p, __shfl_xor(p, m, 64));
            float d = __fsub_rn(__fadd_rn(zs, esq[c]), __fmul_rn(2.0f, p));
            ull kk = ((ull)__float_as_uint(d) << 32) | (unsigned)c;
            bestk = kk < bestk ? kk : bestk;
        }
        winner = (int)(unsigned)(bestk & 0xFFFFFFFFu);
    }

    // one-hot row write (winner is wave-uniform); 4 x 1KB coalesced stores per wave
    float* np = nearest + ((size_t)row << 10);
    #pragma unroll
    for (int q = 0; q < 4; ++q) {
        int cb4 = (q << 8) + (lane << 2);
        float4 v = { winner == cb4     ? 1.f : 0.f, winner == cb4 + 1 ? 1.f : 0.f,
                     winner == cb4 + 2 ? 1.f : 0.f, winner == cb4 + 3 ? 1.f : 0.f };
        *(float4*)(np + cb4) = v;
    }
    if (lane == 0) {
        idxarr[row] = winner;
        out_idx[row] = (float)winner;
        atomicAdd(&hist[winner], 1);
    }
}

// ---------------- zq gather + straight-through output + loss partials ----------------
// thread handles 4 elements along C at fixed (b,hw): z/out accesses coalesced per
// wave (consecutive hw); emb gather is one float4 (16B/line instead of 4B/line)
__global__ void zq_loss_kernel(const float* __restrict__ z, const float* __restrict__ emb,
                               const int* __restrict__ idxarr, float* __restrict__ outzq,
                               double* __restrict__ lossp) {
    int g  = blockIdx.x * 256 + threadIdx.x;          // [0, 2^21)
    int hw = g & 1023;
    int c0 = ((g >> 10) & 63) << 2;
    int b  = g >> 16;
    int n  = (b << 10) | hw;
    int idx = idxarr[n];

    float4 zq = *(const float4*)(emb + (size_t)idx * EMB_D + c0);
    size_t o = ((size_t)b << 18) + ((size_t)c0 << 10) + hw;

    double s = 0.0;
    #pragma unroll
    for (int e = 0; e < 4; ++e) {
        float zc = z[o + ((size_t)e << 10)];
        float q  = (e == 0) ? zq.x : (e == 1) ? zq.y : (e == 2) ? zq.z : zq.w;
        float diff = __fsub_rn(q, zc);
        outzq[o + ((size_t)e << 10)] = __fadd_rn(zc, diff);   // same ops as ref
        s += (double)__fmul_rn(diff, diff);
    }

    __shared__ double sd[256];
    sd[threadIdx.x] = s;
    __syncthreads();
    for (int st = 128; st > 0; st >>= 1) {
        if (threadIdx.x < st) sd[threadIdx.x] += sd[threadIdx.x + st];
        __syncthreads();
    }
    if (threadIdx.x == 0) lossp[blockIdx.x] = sd[0];
}

// ---------------- scalars ----------------
__global__ void finalize_scalars(const double* __restrict__ lossp,
                                 const int* __restrict__ hist,
                                 float* __restrict__ out_loss,
                                 float* __restrict__ out_perp) {
    __shared__ double sd[1024];
    int t = threadIdx.x;

    double s = 0.0;
    for (int i = 0; i < 8; ++i) s += lossp[t + (i << 10)];
    sd[t] = s;
    __syncthreads();
    for (int st = 512; st > 0; st >>= 1) {
        if (t < st) sd[t] += sd[t + st];
        __syncthreads();
    }
    if (t == 0) {
        double loss = 1.25 * (sd[0] / 8388608.0);
        *out_loss = (float)loss;
    }
    __syncthreads();

    float p = (float)hist[t] * (1.0f / 32768.0f);
    float term = __fmul_rn(p, logf(__fadd_rn(p, 1e-10f)));
    sd[t] = (double)term;
    __syncthreads();
    for (int st = 512; st > 0; st >>= 1) {
        if (t < st) sd[t] += sd[t + st];
        __syncthreads();
    }
    if (t == 0) *out_perp = expf(-(float)sd[0]);
}

// ---------------- launch ----------------
extern "C" void kernel_launch(void* const* d_in, const int* in_sizes, int n_in,
                              void* d_out, int out_size, void* d_ws, size_t ws_size,
                              hipStream_t stream) {
    const float* z   = (const float*)d_in[0];
    const float* emb = (const float*)d_in[1];
    float* out = (float*)d_out;
    char*  ws  = (char*)d_ws;

    int*     idxarr = (int*)(ws + WS_IDX);
    int*     hist   = (int*)(ws + WS_HIST);
    float*   zsq    = (float*)(ws + WS_ZSQ);
    float*   esq    = (float*)(ws + WS_ESQ);
    double*  lossp  = (double*)(ws + WS_LOSSP);
    _Float16* eh    = (_Float16*)(ws + WS_EH);

    // stream-ordered scratch inside d_out (see layout comments at top)
    ull*      keys2 = (ull*)d_out;                          // zq region, pre-zq_loss
    _Float16* zh    = (_Float16*)((char*)d_out + ZH_BYTE_OFF); // one-hot region, pre-refine

    split_z<<<256, 256, 0, stream>>>(z, zh, zsq);
    split_e<<<N_EMB, 256, 0, stream>>>(emb, eh);
    esq_kernel<<<N_EMB / 256, 256, 0, stream>>>(emb, esq, hist);

    gemm_mfma_argmin<<<(N_ROWS / 128) * (N_EMB / 128), 256, 0, stream>>>(
        zh, eh, zsq, esq, keys2);

    refine_rows<<<N_ROWS / 4, 256, 0, stream>>>(keys2, z, emb, zsq, esq,
                                                idxarr, out + OUT_IDX,
                                                out + OUT_NEAREST, hist);
    zq_loss_kernel<<<2097152 / 256, 256, 0, stream>>>(z, emb, idxarr, out, lossp);
    finalize_scalars<<<1, 1024, 0, stream>>>(lossp, hist,
                                             out + OUT_LOSS, out + OUT_PERP);
}

// Round 6
// 85.769 us; speedup vs baseline: 3.7418x; 1.7068x over previous
//
#include <hip/hip_runtime.h>

// ---------------- problem constants ----------------
#define N_EMB  1024
#define EMB_D  256
#define HW     1024

// d_out layout (floats)
#define OUT_ZQ      0
#define OUT_LOSS    8388608
#define OUT_PERP    8388609
#define OUT_NEAREST 8388610
#define OUT_IDX     41943042

// ws layout (bytes)
#define WS_HIST   0        // 1024*4
#define WS_ESQ    4096     // 1024*4
#define WS_LOSSP  8192     // 512*8
#define WS_EH     12288    // 1024*256*2
#define WS_TOTAL  536576

typedef unsigned long long ull;
typedef _Float16 half8 __attribute__((ext_vector_type(8)));
typedef float f32x4 __attribute__((ext_vector_type(4)));
typedef ull ull2 __attribute__((ext_vector_type(2)));

// LDS map (bytes), total 55808 (54.5 KB -> 2 blocks/CU, 512-block grid co-resident)
#define L_A     0        // 32KB: A f16 [64 rows][512B] swizzled; aliased as keys after gemm
#define L_B     32768    // 16KB: B tile [128 cols][128B] swizzled (round-5 layout)
#define L_ESQ   49152    // 4KB: esq copy
#define L_ZSQ   53248    // 256B
#define L_WIN   53504    // 256B
#define L_RED   53760    // 2KB: zsq halves temp, later loss doubles
#define L_TOT   55808

__device__ __forceinline__ void gload16(const void* g, void* l) {
    __builtin_amdgcn_global_load_lds(
        (const __attribute__((address_space(1))) unsigned int*)g,
        (__attribute__((address_space(3))) unsigned int*)l, 16, 0, 0);
}

__device__ __forceinline__ float pairwise8_combine(const float r[8]) {
    return __fadd_rn(__fadd_rn(__fadd_rn(r[0], r[1]), __fadd_rn(r[2], r[3])),
                     __fadd_rn(__fadd_rn(r[4], r[5]), __fadd_rn(r[6], r[7])));
}

// ---------------- fp16 h-part of emb ----------------
__global__ void split_e(const float* __restrict__ emb, _Float16* __restrict__ eh) {
    int c = blockIdx.x;
    int k = threadIdx.x;
    eh[c * EMB_D + k] = (_Float16)emb[c * EMB_D + k];
}

// ---------------- esq (numpy pairwise) + hist zeroing ----------------
__global__ void esq_kernel(const float* __restrict__ emb, float* __restrict__ esq,
                           int* __restrict__ hist) {
    int c = blockIdx.x * 256 + threadIdx.x;
    const float* p = emb + (size_t)c * EMB_D;
    float tot[2];
    #pragma unroll
    for (int h = 0; h < 2; ++h) {
        float r[8];
        #pragma unroll
        for (int i = 0; i < 8; ++i) {
            float x = p[h * 128 + i];
            r[i] = __fmul_rn(x, x);
        }
        for (int k = 8; k < 128; k += 8) {
            #pragma unroll
            for (int i = 0; i < 8; ++i) {
                float x = p[h * 128 + k + i];
                r[i] = __fadd_rn(r[i], __fmul_rn(x, x));
            }
        }
        tot[h] = pairwise8_combine(r);
    }
    esq[c] = __fadd_rn(tot[0], tot[1]);
    hist[c] = 0;
}

// ---------------- fused VQ: split+zsq+gemm+argmin+refine+onehot+zq+loss ------------
// 512 blocks (b 32 x hw-chunk 16), 64 rows/block, 256 threads = 4 waves (2 wm x 2 wn)
__global__ __launch_bounds__(256) void fused_vq(
        const float* __restrict__ z, const float* __restrict__ emb,
        const _Float16* __restrict__ eh, const float* __restrict__ esq,
        float* __restrict__ out, int* __restrict__ hist,
        double* __restrict__ lossp) {
    __shared__ __align__(16) char lds[L_TOT];
    int t = threadIdx.x, bid = blockIdx.x;
    int b = bid >> 4, hw0 = (bid & 15) << 6;
    int lane = t & 63, wave = t >> 6;
    int wm = wave >> 1, wn = wave & 1;
    int l15 = lane & 15, lq = lane >> 4;

    // ---- P0: esq->LDS (threads 128-255); A f16 + zsq halves (threads 0-127) ----
    if (t >= 128) {
        int i = t - 128;
        #pragma unroll
        for (int q = 0; q < 8; ++q)
            *(float*)(lds + L_ESQ + (q * 128 + i) * 4) = esq[q * 128 + i];
    } else {
        int nl = t & 63, h = (t >> 6) & 1;
        const float* zp = z + ((size_t)b << 18) + hw0 + nl;
        int kb = h << 7;                      // halfword base in row
        int abase = L_A + nl * 512;
        int sw = (nl & 7) << 4;
        float r[8];
        {   half8 hv;
            #pragma unroll
            for (int e = 0; e < 8; ++e) {
                float x = zp[(size_t)(kb + e) << 10];
                hv[e] = (_Float16)x;
                r[e] = __fmul_rn(x, x);
            }
            *(half8*)(lds + abase + (((kb << 1)) ^ sw)) = hv;
        }
        for (int c8 = 1; c8 < 16; ++c8) {
            half8 hv;
            #pragma unroll
            for (int e = 0; e < 8; ++e) {
                float x = zp[(size_t)(kb + c8 * 8 + e) << 10];
                hv[e] = (_Float16)x;
                r[e] = __fadd_rn(r[e], __fmul_rn(x, x));
            }
            *(half8*)(lds + abase + (((kb << 1) + c8 * 16) ^ sw)) = hv;
        }
        *(float*)(lds + L_RED + (h * 64 + nl) * 4) = pairwise8_combine(r);
    }
    __syncthreads();
    if (t < 64) {   // numpy: zsq = fadd(half0, half1)
        float t0 = *(float*)(lds + L_RED + t * 4);
        float t1 = *(float*)(lds + L_RED + 256 + t * 4);
        *(float*)(lds + L_ZSQ + t * 4) = __fadd_rn(t0, t1);
    }
    __syncthreads();

    // ---- offsets ----
    int aoffs[2][2], boffs[4][2];
    #pragma unroll
    for (int i = 0; i < 2; ++i) {
        int r = wm * 32 + i * 16 + l15;
        #pragma unroll
        for (int kc = 0; kc < 2; ++kc)
            aoffs[i][kc] = L_A + r * 512 + ((kc * 64 + lq * 16) ^ ((r & 7) << 4));
    }
    #pragma unroll
    for (int j = 0; j < 4; ++j) {
        int c = wn * 64 + j * 16 + l15;
        #pragma unroll
        for (int kc = 0; kc < 2; ++kc)
            boffs[j][kc] = L_B + c * 128 + ((kc * 64 + lq * 16) ^ ((c & 7) << 4));
    }
    int bsrc[4], bdst[4];
    #pragma unroll
    for (int is = 0; is < 4; ++is) {
        int o = is * 4096 + t * 16;
        int col = o >> 7;
        int K = (o & 127) ^ ((col & 7) << 4);
        bsrc[is] = col * 256 + (K >> 1);      // halfword offset within eh col-block
        bdst[is] = L_B + o;
    }
    float zs[8];
    #pragma unroll
    for (int s = 0; s < 8; ++s) {
        int row = wm * 32 + (s >> 2) * 16 + lq * 4 + (s & 3);
        zs[s] = *(const float*)(lds + L_ZSQ + row * 4);
    }
    ull k1[8], k2[8];
    #pragma unroll
    for (int s = 0; s < 8; ++s) { k1[s] = ~0ULL; k2[s] = ~0ULL; }

    // ---- P1: gemm, 8 col-tiles x 4 k-steps, per-lane top-2 per 32-col slice ----
    for (int cbt = 0; cbt < 8; ++cbt) {
        f32x4 acc[2][4];
        #pragma unroll
        for (int i = 0; i < 2; ++i)
            #pragma unroll
            for (int j = 0; j < 4; ++j) acc[i][j] = (f32x4){0.f, 0.f, 0.f, 0.f};

        for (int kt = 0; kt < 4; ++kt) {
            __syncthreads();                   // prev B consumed
            #pragma unroll
            for (int is = 0; is < 4; ++is)
                gload16(eh + cbt * 32768 + kt * 64 + bsrc[is], lds + bdst[is]);
            __syncthreads();                   // B ready (vmcnt drained)

            half8 a[2][2], bb[4][2];
            #pragma unroll
            for (int i = 0; i < 2; ++i) {
                a[i][0] = *(const half8*)(lds + aoffs[i][0] + kt * 128);
                a[i][1] = *(const half8*)(lds + aoffs[i][1] + kt * 128);
            }
            #pragma unroll
            for (int j = 0; j < 4; ++j) {
                bb[j][0] = *(const half8*)(lds + boffs[j][0]);
                bb[j][1] = *(const half8*)(lds + boffs[j][1]);
            }
            #pragma unroll
            for (int i = 0; i < 2; ++i)
                #pragma unroll
                for (int j = 0; j < 4; ++j) {
                    acc[i][j] = __builtin_amdgcn_mfma_f32_16x16x32_f16(a[i][0], bb[j][0], acc[i][j], 0, 0, 0);
                    acc[i][j] = __builtin_amdgcn_mfma_f32_16x16x32_f16(a[i][1], bb[j][1], acc[i][j], 0, 0, 0);
                }
        }
        // d = fl(fl(zs+es) - fl(2*dot)); insert into per-lane top-2
        float es[4];
        #pragma unroll
        for (int j = 0; j < 4; ++j)
            es[j] = *(const float*)(lds + L_ESQ + ((cbt << 7) + wn * 64 + j * 16 + l15) * 4);
        #pragma unroll
        for (int i = 0; i < 2; ++i)
            #pragma unroll
            for (int r = 0; r < 4; ++r) {
                const int s = i * 4 + r;
                float zsv = zs[s];
                #pragma unroll
                for (int j = 0; j < 4; ++j) {
                    float d = __fsub_rn(__fadd_rn(zsv, es[j]), __fmul_rn(2.0f, acc[i][j][r]));
                    int cg = (cbt << 7) + wn * 64 + j * 16 + l15;
                    ull key = ((ull)__float_as_uint(d) << 32) | (unsigned)cg;
                    if (key < k1[s]) { k2[s] = k1[s]; k1[s] = key; }
                    else if (key < k2[s]) { k2[s] = key; }
                }
            }
    }

    // ---- P2: keys -> LDS (alias dead A area): [row][32 slots][2] ull ----
    __syncthreads();                           // all A reads done
    #pragma unroll
    for (int s = 0; s < 8; ++s) {
        int row = wm * 32 + (s >> 2) * 16 + lq * 4 + (s & 3);
        *(ull2*)(lds + L_A + row * 512 + ((wn << 4) + l15) * 16) = (ull2){k1[s], k2[s]};
    }
    __syncthreads();

    // ---- P3/P4: per-row refine (margin 2e-4, exact fp32 slow path) + outputs ----
    for (int rr = 0; rr < 16; ++rr) {
        int row = wave * 16 + rr;
        ull k = *(const ull*)(lds + L_A + row * 512 + lane * 8);
        ull kmin = k;
        #pragma unroll
        for (int m = 1; m < 64; m <<= 1) {
            ull o = __shfl_xor(kmin, m, 64);
            kmin = o < kmin ? o : kmin;
        }
        float dmin = __uint_as_float((unsigned)(kmin >> 32));
        float dme  = __uint_as_float((unsigned)(k >> 32));
        bool cand = dme <= __fadd_rn(dmin, 2e-4f);
        ull bal = __ballot(cand);
        int winner;
        if (__popcll(bal) == 1) {
            winner = (int)(unsigned)(kmin & 0xFFFFFFFFu);   // provably exact
        } else {
            const float* zp2 = z + ((size_t)b << 18) + hw0 + row;
            float zr[4];
            #pragma unroll
            for (int e = 0; e < 4; ++e) zr[e] = zp2[(size_t)(lane + 64 * e) << 10];
            float zsr = *(const float*)(lds + L_ZSQ + row * 4);
            ull bestk = ~0ULL;
            while (bal) {
                int src = __ffsll(bal) - 1;
                bal &= bal - 1;
                ull ck = __shfl(k, src, 64);
                int c = (int)(unsigned)(ck & 0xFFFFFFFFu);
                const float* ep = emb + (size_t)c * EMB_D;
                float p = __fmul_rn(zr[3], ep[lane + 192]);
                p = __builtin_fmaf(zr[2], ep[lane + 128], p);
                p = __builtin_fmaf(zr[1], ep[lane + 64], p);
                p = __builtin_fmaf(zr[0], ep[lane], p);
                #pragma unroll
                for (int m = 1; m < 64; m <<= 1)
                    p = __fadd_rn(p, __shfl_xor(p, m, 64));
                float ec = *(const float*)(lds + L_ESQ + c * 4);
                float d = __fsub_rn(__fadd_rn(zsr, ec), __fmul_rn(2.0f, p));
                ull kk = ((ull)__float_as_uint(d) << 32) | (unsigned)c;
                bestk = kk < bestk ? kk : bestk;
            }
            winner = (int)(unsigned)(bestk & 0xFFFFFFFFu);
        }
        // one-hot + idx + hist (winner is wave-uniform)
        size_t n = (size_t)bid * 64 + row;
        float* np = out + OUT_NEAREST + (n << 10);
        #pragma unroll
        for (int q = 0; q < 4; ++q) {
            int c4 = q * 256 + lane * 4;
            float4 v = { winner == c4     ? 1.f : 0.f, winner == c4 + 1 ? 1.f : 0.f,
                         winner == c4 + 2 ? 1.f : 0.f, winner == c4 + 3 ? 1.f : 0.f };
            *(float4*)(np + c4) = v;
        }
        if (lane == 0) {
            out[OUT_IDX + n] = (float)winner;
            atomicAdd(&hist[winner], 1);
            *(int*)(lds + L_WIN + row * 4) = winner;
        }
    }
    __syncthreads();                           // winners ready

    // ---- P5: zq gather + straight-through + loss partial ----
    {
        int hwl = t & 63, cq = t >> 6;
        int widx = *(const int*)(lds + L_WIN + hwl * 4);
        const float* zp3 = z + ((size_t)b << 18) + hw0 + hwl;
        float* oq = out + OUT_ZQ + ((size_t)b << 18) + hw0 + hwl;
        const float* er = emb + (size_t)widx * EMB_D;
        double s = 0.0;
        for (int cg = 0; cg < 16; ++cg) {
            int c0 = cq * 64 + cg * 4;
            float4 ev = *(const float4*)(er + c0);
            float evv[4] = {ev.x, ev.y, ev.z, ev.w};
            #pragma unroll
            for (int e = 0; e < 4; ++e) {
                size_t off = (size_t)(c0 + e) << 10;
                float zc = zp3[off];
                float diff = __fsub_rn(evv[e], zc);
                oq[off] = __fadd_rn(zc, diff);            // zc + (zq - zc), ref ops
                s += (double)__fmul_rn(diff, diff);
            }
        }
        *(double*)(lds + L_RED + t * 8) = s;
        __syncthreads();
        for (int st = 128; st > 0; st >>= 1) {
            if (t < st) {
                double o = *(double*)(lds + L_RED + (t + st) * 8);
                *(double*)(lds + L_RED + t * 8) += o;
            }
            __syncthreads();
        }
        if (t == 0) lossp[bid] = *(double*)(lds + L_RED);
    }
}

// ---------------- scalars ----------------
__global__ void finalize_scalars(const double* __restrict__ lossp,
                                 const int* __restrict__ hist,
                                 float* __restrict__ out_loss,
                                 float* __restrict__ out_perp) {
    __shared__ double sd[1024];
    int t = threadIdx.x;

    sd[t] = (t < 512) ? lossp[t] : 0.0;
    __syncthreads();
    for (int st = 512; st > 0; st >>= 1) {
        if (t < st) sd[t] += sd[t + st];
        __syncthreads();
    }
    if (t == 0) {
        double loss = 1.25 * (sd[0] / 8388608.0);
        *out_loss = (float)loss;
    }
    __syncthreads();

    float p = (float)hist[t] * (1.0f / 32768.0f);
    float term = __fmul_rn(p, logf(__fadd_rn(p, 1e-10f)));
    sd[t] = (double)term;
    __syncthreads();
    for (int st = 512; st > 0; st >>= 1) {
        if (t < st) sd[t] += sd[t + st];
        __syncthreads();
    }
    if (t == 0) *out_perp = expf(-(float)sd[0]);
}

// ---------------- launch ----------------
extern "C" void kernel_launch(void* const* d_in, const int* in_sizes, int n_in,
                              void* d_out, int out_size, void* d_ws, size_t ws_size,
                              hipStream_t stream) {
    const float* z   = (const float*)d_in[0];
    const float* emb = (const float*)d_in[1];
    float* out = (float*)d_out;
    char*  ws  = (char*)d_ws;

    int*      hist  = (int*)(ws + WS_HIST);
    float*    esq   = (float*)(ws + WS_ESQ);
    double*   lossp = (double*)(ws + WS_LOSSP);
    _Float16* eh    = (_Float16*)(ws + WS_EH);

    esq_kernel<<<N_EMB / 256, 256, 0, stream>>>(emb, esq, hist);
    split_e<<<N_EMB, 256, 0, stream>>>(emb, eh);

    fused_vq<<<512, 256, 0, stream>>>(z, emb, eh, esq, out, hist, lossp);

    finalize_scalars<<<1, 1024, 0, stream>>>(lossp, hist,
                                             out + OUT_LOSS, out + OUT_PERP);
}